// Round 1
// baseline (241.862 us; speedup 1.0000x reference)
//
#include <hip/hip_runtime.h>
#include <hip/hip_bf16.h>
#include <math.h>

// Problem constants (from reference)
#define PBOX 2000
#define CC   512
#define HH   192
#define WW   336
#define HWSZ (HH * WW)        // 64512
#define NCOL4 (HWSZ / 4)      // 16128 float4 spatial columns
#define SATW 340              // padded SAT row width (>= WW+1, mult of 4)
#define SATH (HH + 1)         // 193

// ---------------------------------------------------------------------------
// K1: channel mean.  g[h][w] = mean_c x[c][h][w]
// Block: 256 threads = 8 channel-subgroups x 32 float4-columns.
// Grid: NCOL4/32 = 504 blocks.
// ---------------------------------------------------------------------------
__global__ __launch_bounds__(256) void k_chanmean(const float* __restrict__ x,
                                                  float* __restrict__ g) {
    const int t    = threadIdx.x;
    const int sub  = t >> 5;          // 0..7  channel subgroup
    const int o    = t & 31;          // 0..31 output column within block
    const int col4 = blockIdx.x * 32 + o;

    const float4* __restrict__ x4 = (const float4*)x;
    const int cbase = sub * (CC / 8); // 64 channels per subgroup

    float4 acc = make_float4(0.f, 0.f, 0.f, 0.f);
#pragma unroll 4
    for (int c = 0; c < CC / 8; ++c) {
        float4 v = x4[(size_t)(cbase + c) * NCOL4 + col4];
        acc.x += v.x; acc.y += v.y; acc.z += v.z; acc.w += v.w;
    }

    __shared__ float4 red[256];
    red[t] = acc;
    __syncthreads();

    if (sub == 0) {
        float4 s = red[o];
#pragma unroll
        for (int k = 1; k < 8; ++k) {
            float4 v = red[k * 32 + o];
            s.x += v.x; s.y += v.y; s.z += v.z; s.w += v.w;
        }
        const float inv = 1.0f / (float)CC;
        s.x *= inv; s.y *= inv; s.z *= inv; s.w *= inv;
        ((float4*)g)[col4] = s;
    }
}

// ---------------------------------------------------------------------------
// K2: summed-area table with zero-padded first row/col.
// sat is [SATH][SATW]; valid region rows 0..192, cols 0..336.
// Single block, 512 threads.
// ---------------------------------------------------------------------------
__global__ __launch_bounds__(512) void k_sat(const float* __restrict__ g,
                                             float* __restrict__ sat) {
    const int t = threadIdx.x;

    // zero row 0 (cols 0..WW) and col 0 (rows 0..HH)
    for (int i = t; i <= WW; i += 512) sat[i] = 0.f;
    for (int i = t; i <= HH; i += 512) sat[(size_t)i * SATW] = 0.f;

    // row scans: thread r handles image row r -> sat row r+1, cols 1..336
    if (t < HH) {
        const float4* __restrict__ g4 = (const float4*)(g + (size_t)t * WW);
        float* __restrict__ sr = sat + (size_t)(t + 1) * SATW + 1;
        float run = 0.f;
        for (int q = 0; q < WW / 4; ++q) {
            float4 v = g4[q];
            float s0 = run + v.x;
            float s1 = s0 + v.y;
            float s2 = s1 + v.z;
            float s3 = s2 + v.w;
            run = s3;
            sr[q * 4 + 0] = s0;
            sr[q * 4 + 1] = s1;
            sr[q * 4 + 2] = s2;
            sr[q * 4 + 3] = s3;
        }
    }
    __syncthreads();

    // column scans: thread c handles SAT column c+1, rows 1..192
    if (t < WW) {
        float* __restrict__ scp = sat + (t + 1);
        float run = 0.f;
        for (int y = 1; y <= HH; ++y) {
            run += scp[(size_t)y * SATW];
            scp[(size_t)y * SATW] = run;
        }
    }
}

// ---------------------------------------------------------------------------
// K3: box scores + top-(select_num+1) threshold + sigmoid.
// Single block, 256 threads, 8 boxes/thread (2048 slots, pad with -inf).
// ---------------------------------------------------------------------------
__global__ __launch_bounds__(256) void k_boxes(const float4* __restrict__ bbox,
                                               const float* __restrict__ scale,
                                               const int* __restrict__ selnum,
                                               const float* __restrict__ sat,
                                               float* __restrict__ out) {
    constexpr int TPB = 256;
    constexpr int BPT = 8;      // 2048 slots >= PBOX
    constexpr int PPAD = TPB * BPT;

    __shared__ float sc[PPAD];  // working copy for extraction
    __shared__ float topv[64];
    __shared__ float wval[4];
    __shared__ int   widx[4];

    const int t = threadIdx.x;
    const float sx = scale[1];
    const float sy = scale[0];

    float myscore[BPT];
#pragma unroll
    for (int i = 0; i < BPT; ++i) {
        const int p = t + i * TPB;
        float score = -INFINITY;
        if (p < PBOX) {
            float4 b = bbox[p];
            int x1 = min(max((int)floorf(b.x / sx), 0), WW - 1);
            int y1 = min(max((int)floorf(b.y / sy), 0), HH - 1);
            int x2 = min(max((int)floorf(b.z / sx), 0), WW - 1);
            int y2 = min(max((int)floorf(b.w / sy), 0), HH - 1);
            float s = sat[(size_t)(y2 + 1) * SATW + (x2 + 1)]
                    - sat[(size_t)y1 * SATW + (x2 + 1)]
                    - sat[(size_t)(y2 + 1) * SATW + x1]
                    + sat[(size_t)y1 * SATW + x1];
            float area = (float)((y2 - y1 + 1) * (x2 - x1 + 1));
            score = s / area;
        }
        myscore[i] = score;
        sc[p < PBOX ? p : (t + i * TPB)] = score; // p always == t+i*TPB
    }
    __syncthreads();

    const int sn = *selnum;
    const int rounds = min(sn + 1, 64);

    for (int r = 0; r < rounds; ++r) {
        // per-thread max over its slots
        float bv = -INFINITY;
        int bi = 0;
#pragma unroll
        for (int i = 0; i < BPT; ++i) {
            const int p = t + i * TPB;
            const float v = sc[p];
            if (v > bv) { bv = v; bi = p; }
        }
        // wave (64-lane) argmax reduce
        for (int off = 32; off > 0; off >>= 1) {
            float ov = __shfl_down(bv, off);
            int   oi = __shfl_down(bi, off);
            if (ov > bv) { bv = ov; bi = oi; }
        }
        const int wid = t >> 6;
        if ((t & 63) == 0) { wval[wid] = bv; widx[wid] = bi; }
        __syncthreads();
        if (t == 0) {
            float fv = wval[0]; int fi = widx[0];
#pragma unroll
            for (int w = 1; w < 4; ++w)
                if (wval[w] > fv) { fv = wval[w]; fi = widx[w]; }
            topv[r] = fv;
            sc[fi] = -INFINITY;
        }
        __syncthreads();
    }

    const float thresh = 0.5f * (topv[sn - 1] + topv[sn]);

#pragma unroll
    for (int i = 0; i < BPT; ++i) {
        const int p = t + i * TPB;
        if (p < PBOX) {
            const float z = (myscore[i] - thresh) * 100.0f;
            out[p] = 1.0f / (1.0f + expf(-z));
        }
    }
}

// ---------------------------------------------------------------------------
extern "C" void kernel_launch(void* const* d_in, const int* in_sizes, int n_in,
                              void* d_out, int out_size, void* d_ws, size_t ws_size,
                              hipStream_t stream) {
    const float* x     = (const float*)d_in[0];
    const float* bbox  = (const float*)d_in[1];
    const float* scale = (const float*)d_in[2];
    const int*   seln  = (const int*)d_in[3];

    float* g   = (float*)d_ws;              // HWSZ floats   (258 KB)
    float* sat = g + HWSZ;                  // SATH*SATW floats (~257 KB)

    k_chanmean<<<NCOL4 / 32, 256, 0, stream>>>(x, g);
    k_sat<<<1, 512, 0, stream>>>(g, sat);
    k_boxes<<<1, 256, 0, stream>>>((const float4*)bbox, scale, seln, sat,
                                   (float*)d_out);
}

// Round 2
// 240.258 us; speedup vs baseline: 1.0067x; 1.0067x over previous
//
#include <hip/hip_runtime.h>
#include <hip/hip_bf16.h>
#include <math.h>

// Problem constants (from reference)
#define PBOX 2000
#define CC   512
#define HH   192
#define WW   336
#define HWSZ (HH * WW)        // 64512
#define NCOL4 (HWSZ / 4)      // 16128 float4 spatial columns
#define SATW 340              // padded SAT row width (>= WW+1, mult of 4)
#define SATH (HH + 1)         // 193

// ---------------------------------------------------------------------------
// K1: channel mean.  g[h][w] = mean_c x[c][h][w]
// Block: 256 threads = 8 channel-subgroups x 32 float4-columns.
// Grid: NCOL4/32 = 504 blocks.  Fully coalesced float4 loads; 8-deep unroll
// keeps 8 independent 16B loads in flight per lane.
// ---------------------------------------------------------------------------
__global__ __launch_bounds__(256) void k_chanmean(const float* __restrict__ x,
                                                  float* __restrict__ g) {
    const int t    = threadIdx.x;
    const int sub  = t >> 5;          // 0..7  channel subgroup
    const int o    = t & 31;          // 0..31 output column within block
    const int col4 = blockIdx.x * 32 + o;

    const float4* __restrict__ x4 = (const float4*)x;
    const int cbase = sub * (CC / 8); // 64 channels per subgroup

    float4 acc = make_float4(0.f, 0.f, 0.f, 0.f);
#pragma unroll 8
    for (int c = 0; c < CC / 8; ++c) {
        float4 v = x4[(size_t)(cbase + c) * NCOL4 + col4];
        acc.x += v.x; acc.y += v.y; acc.z += v.z; acc.w += v.w;
    }

    __shared__ float4 red[256];
    red[t] = acc;
    __syncthreads();

    if (sub == 0) {
        float4 s = red[o];
#pragma unroll
        for (int k = 1; k < 8; ++k) {
            float4 v = red[k * 32 + o];
            s.x += v.x; s.y += v.y; s.z += v.z; s.w += v.w;
        }
        const float inv = 1.0f / (float)CC;
        s.x *= inv; s.y *= inv; s.z *= inv; s.w *= inv;
        ((float4*)g)[col4] = s;
    }
}

// ---------------------------------------------------------------------------
// K2 (fused): SAT build + box scores + top-(sn+1) threshold + sigmoid.
// Single block, 512 threads.
//   phase 1: zero pad row/col; row prefix scans (threads 0..191)
//   phase 2: column prefix scans (threads 0..335), 16-row batched prefetch
//   phase 3: per-box scores into LDS (+registers)
//   phase 4: wave-0-only iterative argmax extraction (no barriers in loop)
//   phase 5: sigmoid((score - thresh) * 100)
// ---------------------------------------------------------------------------
__global__ __launch_bounds__(512) void k_sat_boxes(const float* __restrict__ g,
                                                   float* __restrict__ sat,
                                                   const float4* __restrict__ bbox,
                                                   const float* __restrict__ scale,
                                                   const int* __restrict__ selnum,
                                                   float* __restrict__ out) {
    constexpr int TPB = 512;
    constexpr int BPT = 4;            // 2048 slots >= PBOX
    __shared__ float sc[TPB * BPT];
    __shared__ float s_thresh;

    const int t = threadIdx.x;

    // ---- phase 1: zero pad + row scans -------------------------------------
    for (int i = t; i <= WW; i += TPB) sat[i] = 0.f;
    for (int i = t; i <= HH; i += TPB) sat[(size_t)i * SATW] = 0.f;

    if (t < HH) {
        const float4* __restrict__ g4 = (const float4*)(g + (size_t)t * WW);
        float* __restrict__ sr = sat + (size_t)(t + 1) * SATW + 1;
        float run = 0.f;
#pragma unroll 4
        for (int q = 0; q < WW / 4; ++q) {
            float4 v = g4[q];
            float s0 = run + v.x;
            float s1 = s0 + v.y;
            float s2 = s1 + v.z;
            float s3 = s2 + v.w;
            run = s3;
            sr[q * 4 + 0] = s0;
            sr[q * 4 + 1] = s1;
            sr[q * 4 + 2] = s2;
            sr[q * 4 + 3] = s3;
        }
    }
    __syncthreads();

    // ---- phase 2: column scans, 16-row batches (loads independent) ---------
    if (t < WW) {
        float* __restrict__ scp = sat + (t + 1);
        float run = 0.f;
        for (int y0 = 1; y0 <= HH; y0 += 16) {
            float v[16];
#pragma unroll
            for (int k = 0; k < 16; ++k) v[k] = scp[(size_t)(y0 + k) * SATW];
#pragma unroll
            for (int k = 0; k < 16; ++k) {
                run += v[k];
                scp[(size_t)(y0 + k) * SATW] = run;
            }
        }
    }
    __syncthreads();

    // ---- phase 3: box scores ----------------------------------------------
    const float sx = scale[1];
    const float sy = scale[0];

    float myscore[BPT];
#pragma unroll
    for (int i = 0; i < BPT; ++i) {
        const int p = t + i * TPB;
        float score = -INFINITY;
        if (p < PBOX) {
            float4 b = bbox[p];
            int x1 = min(max((int)floorf(b.x / sx), 0), WW - 1);
            int y1 = min(max((int)floorf(b.y / sy), 0), HH - 1);
            int x2 = min(max((int)floorf(b.z / sx), 0), WW - 1);
            int y2 = min(max((int)floorf(b.w / sy), 0), HH - 1);
            float s = sat[(size_t)(y2 + 1) * SATW + (x2 + 1)]
                    - sat[(size_t)y1 * SATW + (x2 + 1)]
                    - sat[(size_t)(y2 + 1) * SATW + x1]
                    + sat[(size_t)y1 * SATW + x1];
            float area = (float)((y2 - y1 + 1) * (x2 - x1 + 1));
            score = s / area;
        }
        myscore[i] = score;
        sc[p] = score;
    }
    __syncthreads();

    // ---- phase 4: wave-0 extraction of top-(sn+1), barrier-free loop -------
    if (t < 64) {
        const int sn = selnum[0];
        const int rounds = min(sn + 1, 63);
        float va = -INFINITY, vb = -INFINITY;

        for (int r = 0; r < rounds; ++r) {
            // lane t owns slots p = t, t+64, ..., t+64*31 (conflict-free)
            float bv = -INFINITY;
            int bi = t;
#pragma unroll
            for (int k = 0; k < (TPB * BPT) / 64; ++k) {
                const int p = k * 64 + t;
                const float v = sc[p];
                if (v > bv) { bv = v; bi = p; }
            }
            // 64-lane butterfly argmax
#pragma unroll
            for (int off = 32; off > 0; off >>= 1) {
                float ov = __shfl_xor(bv, off);
                int   oi = __shfl_xor(bi, off);
                if (ov > bv) { bv = ov; bi = oi; }
            }
            if ((bi & 63) == t) sc[bi] = -INFINITY;  // owner lane clears it
            if (r == sn - 1) va = bv;
            if (r == sn)     vb = bv;
        }
        if (t == 0) s_thresh = 0.5f * (va + vb);
    }
    __syncthreads();

    // ---- phase 5: sigmoid --------------------------------------------------
    const float thresh = s_thresh;
#pragma unroll
    for (int i = 0; i < BPT; ++i) {
        const int p = t + i * TPB;
        if (p < PBOX) {
            const float z = (myscore[i] - thresh) * 100.0f;
            out[p] = 1.0f / (1.0f + expf(-z));
        }
    }
}

// ---------------------------------------------------------------------------
extern "C" void kernel_launch(void* const* d_in, const int* in_sizes, int n_in,
                              void* d_out, int out_size, void* d_ws, size_t ws_size,
                              hipStream_t stream) {
    const float* x     = (const float*)d_in[0];
    const float* bbox  = (const float*)d_in[1];
    const float* scale = (const float*)d_in[2];
    const int*   seln  = (const int*)d_in[3];

    float* g   = (float*)d_ws;              // HWSZ floats   (258 KB)
    float* sat = g + HWSZ;                  // SATH*SATW floats (~257 KB)

    k_chanmean<<<NCOL4 / 32, 256, 0, stream>>>(x, g);
    k_sat_boxes<<<1, 512, 0, stream>>>(g, sat, (const float4*)bbox, scale, seln,
                                       (float*)d_out);
}